// Round 2
// baseline (384.426 us; speedup 1.0000x reference)
//
#include <hip/hip_runtime.h>

#define NN 50000
#define SNEI 16

typedef unsigned short ushort_t;
typedef unsigned int uint_t;
typedef unsigned long long u64;
typedef __attribute__((ext_vector_type(8))) short bhalf8;
typedef __attribute__((ext_vector_type(4))) float facc4;

__device__ __forceinline__ float b2f(uint_t u) {
    union { uint_t u; float f; } x; x.u = u << 16; return x.f;
}
__device__ __forceinline__ ushort_t f2b(float f) {
    union { float f; uint_t u; } x; x.f = f;
    return (ushort_t)((x.u + 0x7FFFu + ((x.u >> 16) & 1u)) >> 16);
}
__device__ __forceinline__ u64 pack4(float a, float b, float c, float d) {
    return (u64)f2b(a) | ((u64)f2b(b) << 16) | ((u64)f2b(c) << 32) | ((u64)f2b(d) << 48);
}

// ---------------------------------------------------------------------------
// One-time weight permute (fp32 -> bf16) into B-fragment-major order.
// Chunk layout: chunk = (ks*8 + nf)*64 + lane, 8 bf16 per chunk.
// Element j of lane l holds W[k][c] with
//   k = ks*32 + 16*(j>>2) + (l>>4)*4 + (j&3),  c = nf*16 + (l&15).
// Same bijection is used by A-staging, so the MFMA contraction is exact.
// ---------------------------------------------------------------------------
__global__ void permW(const float* __restrict__ prepW,
                      const float* __restrict__ Wx1, const float* __restrict__ Wn1,
                      const float* __restrict__ Wx2, const float* __restrict__ Wn2,
                      ushort_t* __restrict__ dst)
{
    int cid = blockIdx.x * 256 + threadIdx.x;           // 28672 total
    const float* src; int K, hk, q, dbase;
    if (cid < 4096)       { src = prepW; K = 256; hk = 0; q = cid; dbase = 0; }
    else if (cid < 8192)  { int m = cid - 4096;  int mp = m >> 11; q = m & 2047; src = Wx1 + mp*16384; K = 128; hk = 1; dbase = 4096  + mp*2048; }
    else if (cid < 12288) { int m = cid - 8192;  int mp = m >> 11; q = m & 2047; src = Wn1 + mp*16384; K = 128; hk = 1; dbase = 8192  + mp*2048; }
    else if (cid < 20480) { int m = cid - 12288; int mp = m >> 12; q = m & 4095; src = Wx2 + mp*32768; K = 256; hk = 1; dbase = 12288 + mp*4096; }
    else                  { int m = cid - 20480; int mp = m >> 12; q = m & 4095; src = Wn2 + mp*32768; K = 256; hk = 1; dbase = 20480 + mp*4096; }
    int lane = q & 63, nf = (q >> 6) & 7, ks = q >> 9;
    int cl = lane & 15, g = lane >> 4;
    int c = nf * 16 + cl;
    ushort_t tmp[8];
#pragma unroll
    for (int j = 0; j < 8; ++j) {
        int k = ks*32 + ((j >> 2) << 4) + g*4 + (j & 3);
        int sidx = hk ? (((c >> 6)*K + k)*64 + (c & 63)) : (k*128 + c);
        tmp[j] = f2b(src[sidx]);
    }
    u64 lo = (u64)tmp[0] | ((u64)tmp[1] << 16) | ((u64)tmp[2] << 32) | ((u64)tmp[3] << 48);
    u64 hi = (u64)tmp[4] | ((u64)tmp[5] << 16) | ((u64)tmp[6] << 32) | ((u64)tmp[7] << 48);
    u64* o = (u64*)(dst + (size_t)(dbase + q) * 8);
    o[0] = lo; o[1] = hi;
}

// ---------------------------------------------------------------------------
// MFMA GEMM. DUAL=false: prep (bf16 out, no relu). DUAL=true: wave_n=0 does
// X@Wx, wave_n=1 does AGG@Wn, relu, head-interleaved fp32 out.
// XF32: X operand is fp32 (converted to bf16 during staging); else bf16.
// Tile 64 rows x (128|256) virtual cols, BK=64, 4 waves.
// ---------------------------------------------------------------------------
template<bool DUAL, bool XF32>
__global__ __launch_bounds__(256, 2)
void gemm_k(const void* __restrict__ Xv, int px,
            const ushort_t* __restrict__ AG, int pa,
            const ushort_t* __restrict__ Wxp, const ushort_t* __restrict__ Wnp,
            int K, void* __restrict__ outv, int pout, int ocol0)
{
    constexpr int NCH = DUAL ? 3072 : 1536;
    constexpr int NFW = DUAL ? 8 : 4;
    constexpr int WXB = DUAL ? 1024 : 512;
    constexpr int WNB = 2048;
    __shared__ bhalf8 lds[NCH];
    u64* l64 = (u64*)lds;

    const int tid = threadIdx.x;
    const int lane = tid & 63;
    const int wid = tid >> 6;
    const int wave_m = wid >> 1, wave_n = wid & 1;
    const int m0 = blockIdx.x * 64;

    facc4 acc[2][NFW];
    const facc4 z = {0.f, 0.f, 0.f, 0.f};
#pragma unroll
    for (int i = 0; i < 2; ++i)
#pragma unroll
        for (int j = 0; j < NFW; ++j) acc[i][j] = z;

    const int K64 = K >> 6;
    for (int kt = 0; kt < K64; ++kt) {
        // ---- stage X (and AGG) into fragment-major chunks ----
#pragma unroll
        for (int it = 0; it < 2; ++it) {
            int idx = tid + it * 256;          // [0,512): (row, 8-elem chunk a)
            int row = idx >> 3, a = idx & 7;
            int grow = m0 + row; if (grow > NN - 1) grow = NN - 1;
            u64 lo, hi;
            if constexpr (XF32) {
                const float4* gp = (const float4*)((const float*)Xv + (size_t)grow * px + kt*64 + a*8);
                float4 f0 = gp[0], f1 = gp[1];
                lo = pack4(f0.x, f0.y, f0.z, f0.w);
                hi = pack4(f1.x, f1.y, f1.z, f1.w);
            } else {
                const u64* gp = (const u64*)((const ushort_t*)Xv + (size_t)grow * px + kt*64 + a*8);
                lo = gp[0]; hi = gp[1];
            }
            int a2 = a & 3, half = a2 >> 1, g1 = (a2 & 1) << 1;
            int cb = ((a >> 2)*4 + (row >> 4))*64 + (row & 15);
            l64[(cb + g1*16)*2 + half]       = lo;
            l64[(cb + (g1 + 1)*16)*2 + half] = hi;
            if constexpr (DUAL) {
                const u64* ga = (const u64*)(AG + (size_t)grow * pa + kt*64 + a*8);
                u64 lo2 = ga[0], hi2 = ga[1];
                l64[1024 + (cb + g1*16)*2 + half]       = lo2;
                l64[1024 + (cb + (g1 + 1)*16)*2 + half] = hi2;
            }
        }
        // ---- stage W (linear copy of pre-permuted chunks) ----
        {
            const bhalf8* wgx = (const bhalf8*)Wxp + (size_t)kt * 1024;
            const bhalf8* wgn = DUAL ? ((const bhalf8*)Wnp + (size_t)kt * 1024) : nullptr;
#pragma unroll
            for (int it = 0; it < 4; ++it) {
                int idx = tid + it * 256;      // [0,1024)
                lds[WXB + idx] = wgx[idx];
                if constexpr (DUAL) lds[WNB + idx] = wgn[idx];
            }
        }
        __syncthreads();
        // ---- compute ----
        const int aB  = (DUAL && wave_n) ? 512 : 0;
        const int wB  = DUAL ? (wave_n ? WNB : WXB) : WXB;
        const int nfo = DUAL ? 0 : wave_n * 4;
#pragma unroll
        for (int ksl = 0; ksl < 2; ++ksl) {
            bhalf8 a0 = lds[aB + (ksl*4 + wave_m*2 + 0)*64 + lane];
            bhalf8 a1 = lds[aB + (ksl*4 + wave_m*2 + 1)*64 + lane];
#pragma unroll
            for (int nf = 0; nf < NFW; ++nf) {
                bhalf8 b = lds[wB + (ksl*8 + nfo + nf)*64 + lane];
                acc[0][nf] = __builtin_amdgcn_mfma_f32_16x16x32_bf16(a0, b, acc[0][nf], 0, 0, 0);
                acc[1][nf] = __builtin_amdgcn_mfma_f32_16x16x32_bf16(a1, b, acc[1][nf], 0, 0, 0);
            }
        }
        __syncthreads();
    }
    // ---- epilogue: D mapping col=lane&15, row=(lane>>4)*4+reg ----
    const int cl = lane & 15, rg = lane >> 4;
#pragma unroll
    for (int mf2 = 0; mf2 < 2; ++mf2) {
        int rowb = m0 + (wave_m*2 + mf2)*16 + rg*4;
#pragma unroll
        for (int nf = 0; nf < NFW; ++nf) {
            int cpr = DUAL ? nf*16 + cl : (wave_n*4 + nf)*16 + cl;
            int col = DUAL ? (ocol0 + (cpr >> 6)*128 + wave_n*64 + (cpr & 63)) : cpr;
            facc4 v = acc[mf2][nf];
#pragma unroll
            for (int rr = 0; rr < 4; ++rr) {
                int row = rowb + rr;
                if (row < NN) {
                    if constexpr (DUAL) {
                        ((float*)outv)[(size_t)row * pout + col] = fmaxf(v[rr], 0.0f);
                    } else {
                        ((ushort_t*)outv)[(size_t)row * pout + col] = f2b(v[rr]);
                    }
                }
            }
        }
    }
}

// ---------------------------------------------------------------------------
// Gather+mean over bf16 h0 [NN,128] -> bf16 agg [NN,128]. One wave per node.
// ---------------------------------------------------------------------------
__global__ __launch_bounds__(256)
void gatherH0(const ushort_t* __restrict__ h, const int* __restrict__ nb,
              ushort_t* __restrict__ agg)
{
    int wid = threadIdx.x >> 6, lane = threadIdx.x & 63;
    int node = blockIdx.x * 4 + wid;
    const int* np = nb + (size_t)node * SNEI;
    float s0 = 0.f, s1 = 0.f;
#pragma unroll
    for (int s = 0; s < SNEI; ++s) {
        int n2 = np[s];
        uint_t v = ((const uint_t*)(h + (size_t)n2 * 128))[lane];
        s0 += b2f(v & 0xFFFFu); s1 += b2f(v >> 16);
    }
    ((uint_t*)(agg + (size_t)node * 128))[lane] =
        (uint_t)f2b(s0 * 0.0625f) | ((uint_t)f2b(s1 * 0.0625f) << 16);
}

// ---------------------------------------------------------------------------
// Gather+mean over fp32 out[:,0:256] (pitch 512) -> bf16 agg [NN,256].
// ---------------------------------------------------------------------------
__global__ __launch_bounds__(256)
void gatherOut(const float* __restrict__ h, const int* __restrict__ nb,
               ushort_t* __restrict__ agg)
{
    int wid = threadIdx.x >> 6, lane = threadIdx.x & 63;
    int node = blockIdx.x * 4 + wid;
    const int* np = nb + (size_t)node * SNEI;
    float s0 = 0.f, s1 = 0.f, s2 = 0.f, s3 = 0.f;
#pragma unroll
    for (int s = 0; s < SNEI; ++s) {
        int n2 = np[s];
        float4 v = *(const float4*)(h + (size_t)n2 * 512 + lane * 4);
        s0 += v.x; s1 += v.y; s2 += v.z; s3 += v.w;
    }
    *(u64*)(agg + (size_t)node * 256 + lane * 4) =
        pack4(s0 * 0.0625f, s1 * 0.0625f, s2 * 0.0625f, s3 * 0.0625f);
}

// ---------------------------------------------------------------------------
extern "C" void kernel_launch(void* const* d_in, const int* in_sizes, int n_in,
                              void* d_out, int out_size, void* d_ws, size_t ws_size,
                              hipStream_t stream)
{
    const float* feats  = (const float*)d_in[0];
    const float* prepWp = (const float*)d_in[1];
    const float* Wx1    = (const float*)d_in[2];
    const float* Wn1    = (const float*)d_in[3];
    const float* Wx2    = (const float*)d_in[4];
    const float* Wn2    = (const float*)d_in[5];
    const int*   neigh  = (const int*)d_in[6];
    float* out = (float*)d_out;
    ushort_t* ws = (ushort_t*)d_ws;

    ushort_t* perm = ws;                          // 229376 bf16 (458.75 KB)
    ushort_t* h0   = ws + 229376;                 // 50000*128 bf16 (12.8 MB)
    ushort_t* agg  = h0 + (size_t)NN * 128;       // 50000*256 bf16 (25.6 MB)

    permW<<<112, 256, 0, stream>>>(prepWp, Wx1, Wn1, Wx2, Wn2, perm);

    const int GB = (NN + 63) / 64;                // 782
    // prep: h0 = bf16(feats @ prep_W)   [50000,256]@[256,128]
    gemm_k<false, true><<<GB, 256, 0, stream>>>(feats, 256, nullptr, 0,
                                                perm, nullptr, 256, h0, 128, 0);

    for (int mp = 0; mp < 2; ++mp) {
        float* omp = out + (size_t)mp * NN * 512;
        const int* nmp = neigh + (size_t)mp * NN * SNEI;

        gatherH0<<<NN / 4, 256, 0, stream>>>(h0, nmp, agg);
        gemm_k<true, false><<<GB, 256, 0, stream>>>(h0, 128, agg, 128,
            perm + (size_t)(4096  + mp*2048) * 8,
            perm + (size_t)(8192  + mp*2048) * 8,
            128, omp, 512, 0);

        gatherOut<<<NN / 4, 256, 0, stream>>>(omp, nmp, agg);
        gemm_k<true, true><<<GB, 256, 0, stream>>>(omp, 512, agg, 256,
            perm + (size_t)(12288 + mp*4096) * 8,
            perm + (size_t)(20480 + mp*4096) * 8,
            256, omp, 512, 256);
    }
}